// Round 5
// baseline (83.703 us; speedup 1.0000x reference)
//
#include <hip/hip_runtime.h>
#include <math.h>

#define KG 128

typedef float f32x2 __attribute__((ext_vector_type(2)));

// Kernel 1: fold per-gaussian params once.
//  P0[k] = (mux, muy, A', B')   A',B',C' = -0.5*log2e * sigma_inv coeffs
//  P1[k] = (C', alpha, col_r, col_g)
//  P2[k] = col_b
__global__ __launch_bounds__(128) void precompute_params(
    const float* __restrict__ mu,
    const float* __restrict__ alpha,
    const float* __restrict__ color,
    const float* __restrict__ scales,
    const float* __restrict__ thetas,
    float4* __restrict__ P0,
    float4* __restrict__ P1,
    float*  __restrict__ P2)
{
    const int k = threadIdx.x;
    if (k >= KG) return;
    const float mx = mu[2 * k];
    const float my = mu[2 * k + 1];
    const float al = fminf(fmaxf(alpha[k], 0.0f), 1.0f);
    const float cr = fminf(fmaxf(color[3 * k + 0], 0.0f), 255.0f);
    const float cg = fminf(fmaxf(color[3 * k + 1], 0.0f), 255.0f);
    const float cb = fminf(fmaxf(color[3 * k + 2], 0.0f), 255.0f);
    const float sx = fmaxf(scales[2 * k + 0], 0.1f);
    const float sy = fmaxf(scales[2 * k + 1], 0.1f);
    const float th = thetas[k];
    const float c = cosf(th);
    const float s = sinf(th);
    const float i0 = 1.0f / (sx * sx);
    const float i1 = 1.0f / (sy * sy);
    const float a  = c * c * i0 + s * s * i1;
    const float b  = c * s * (i0 - i1);
    const float cc = s * s * i0 + c * c * i1;
    const float f = -0.5f * 1.4426950408889634f;   // fold -0.5*log2(e) -> exp2
    P0[k] = make_float4(mx, my, a * f, 2.0f * b * f);
    P1[k] = make_float4(cc * f, al, cr, cg);
    P2[k] = cb;
}

// Kernel 2: composite. Params are wave-uniform -> uniform-index loads from
// __restrict__ pointers scalarize to s_load_dwordx4 (constant cache, SGPR
// operands folded into VALU). No LDS, no barrier, no VMEM in the K-loop.
// Two pixels per thread as f32x2 -> v_pk_* packed math.
__global__ __launch_bounds__(256) void splat_fwd(
    const float* __restrict__ pos,     // [N,2]
    const float4* __restrict__ P0,
    const float4* __restrict__ P1,
    const float*  __restrict__ P2,
    float* __restrict__ out,           // [N,4]
    int nPairs)
{
    const int t = blockIdx.x * blockDim.x + threadIdx.x;   // pixel-pair index
    if (t >= nPairs) return;

    const float4 pp = reinterpret_cast<const float4*>(pos)[t]; // x0,y0,x1,y1
    const f32x2 px = { pp.x, pp.z };
    const f32x2 py = { pp.y, pp.w };

    f32x2 pa    = { 0.0f, 0.0f };
    f32x2 rprev = { 0.0f, 0.0f };   // unused at k=0 since pa=0
    f32x2 numr  = { 0.0f, 0.0f };
    f32x2 numg  = { 0.0f, 0.0f };
    f32x2 numb  = { 0.0f, 0.0f };

#pragma unroll 4
    for (int k = 0; k < KG; ++k) {
        const float4 q0 = P0[k];
        const float4 q1 = P1[k];
        const float  q2 = P2[k];

        const f32x2 dx = px - q0.x;
        const f32x2 dy = py - q0.y;
        const f32x2 u  = q0.z * dx + q0.w * dy;        // A*dx + B*dy
        const f32x2 e  = dx * u + (q1.x * dy) * dy;    // + C*dy^2

        f32x2 E;
        E.x = __builtin_amdgcn_exp2f(e.x);
        E.y = __builtin_amdgcn_exp2f(e.y);

        const f32x2 w   = q1.y * E;        // alpha_k weight
        const f32x2 omp = 1.0f - pa;
        const f32x2 t1  = w * omp;
        const f32x2 na  = pa + t1;
        const f32x2 nae = na + 1e-8f;

        f32x2 r;
        r.x = __builtin_amdgcn_rcpf(nae.x);
        r.y = __builtin_amdgcn_rcpf(nae.y);

        const f32x2 h = rprev * pa;        // carry: num*h == pc_{k-1}*pa
        numr = numr * h + q1.z * t1;
        numg = numg * h + q1.w * t1;
        numb = numb * h + q2  * t1;

        pa.x = fminf(na.x, 1.0f);
        pa.y = fminf(na.y, 1.0f);
        rprev = r;
    }

    const f32x2 pcr = numr * rprev;
    const f32x2 pcg = numg * rprev;
    const f32x2 pcb = numb * rprev;

    float4 o0, o1;
    o0.x = fminf(fmaxf(pcr.x, 0.0f), 255.0f);
    o0.y = fminf(fmaxf(pcg.x, 0.0f), 255.0f);
    o0.z = fminf(fmaxf(pcb.x, 0.0f), 255.0f);
    o0.w = pa.x * 255.0f;
    o1.x = fminf(fmaxf(pcr.y, 0.0f), 255.0f);
    o1.y = fminf(fmaxf(pcg.y, 0.0f), 255.0f);
    o1.z = fminf(fmaxf(pcb.y, 0.0f), 255.0f);
    o1.w = pa.y * 255.0f;

    float4* o = reinterpret_cast<float4*>(out);
    o[2 * t]     = o0;
    o[2 * t + 1] = o1;
}

extern "C" void kernel_launch(void* const* d_in, const int* in_sizes, int n_in,
                              void* d_out, int out_size, void* d_ws, size_t ws_size,
                              hipStream_t stream) {
    const float* pos    = (const float*)d_in[0];
    const float* mu     = (const float*)d_in[1];
    const float* alpha  = (const float*)d_in[2];
    const float* color  = (const float*)d_in[3];
    const float* scales = (const float*)d_in[4];
    const float* thetas = (const float*)d_in[5];
    float* out = (float*)d_out;

    // Param buffer layout in d_ws (aligned): P0[K] | P1[K] | P2[K]
    float4* P0 = (float4*)d_ws;
    float4* P1 = P0 + KG;
    float*  P2 = (float*)(P1 + KG);

    const int n = in_sizes[0] / 2;       // N pixels
    const int nPairs = n / 2;            // N even (512*512)
    const int block = 256;
    const int grid = (nPairs + block - 1) / block;

    hipLaunchKernelGGL(precompute_params, dim3(1), dim3(128), 0, stream,
                       mu, alpha, color, scales, thetas, P0, P1, P2);
    hipLaunchKernelGGL(splat_fwd, dim3(grid), dim3(block), 0, stream,
                       pos, P0, P1, P2, out, nPairs);
}

// Round 6
// 83.440 us; speedup vs baseline: 1.0032x; 1.0032x over previous
//
#include <hip/hip_runtime.h>
#include <math.h>

#define KG 128
#define CH 8
#define NCHUNK (KG / CH)

typedef float f32x2 __attribute__((ext_vector_type(2)));

// Kernel 1: fold per-gaussian params once into d_ws.
//  P0[k] = (mux, muy, A', B')   A',B',C' = -0.5*log2e * sigma_inv coeffs
//  P1[k] = (C', alpha, col_r, col_g)
//  P2[k] = col_b
__global__ __launch_bounds__(128) void precompute_params(
    const float* __restrict__ mu,
    const float* __restrict__ alpha,
    const float* __restrict__ color,
    const float* __restrict__ scales,
    const float* __restrict__ thetas,
    float4* __restrict__ P0,
    float4* __restrict__ P1,
    float*  __restrict__ P2)
{
    const int k = threadIdx.x;
    if (k >= KG) return;
    const float mx = mu[2 * k];
    const float my = mu[2 * k + 1];
    const float al = fminf(fmaxf(alpha[k], 0.0f), 1.0f);
    const float cr = fminf(fmaxf(color[3 * k + 0], 0.0f), 255.0f);
    const float cg = fminf(fmaxf(color[3 * k + 1], 0.0f), 255.0f);
    const float cb = fminf(fmaxf(color[3 * k + 2], 0.0f), 255.0f);
    const float sx = fmaxf(scales[2 * k + 0], 0.1f);
    const float sy = fmaxf(scales[2 * k + 1], 0.1f);
    const float th = thetas[k];
    const float c = cosf(th);
    const float s = sinf(th);
    const float i0 = 1.0f / (sx * sx);
    const float i1 = 1.0f / (sy * sy);
    const float a  = c * c * i0 + s * s * i1;
    const float b  = c * s * (i0 - i1);
    const float cc = s * s * i0 + c * c * i1;
    const float f = -0.5f * 1.4426950408889634f;   // fold -0.5*log2(e) -> exp2
    P0[k] = make_float4(mx, my, a * f, 2.0f * b * f);
    P1[k] = make_float4(cc * f, al, cr, cg);
    P2[k] = cb;
}

// Kernel 2: chunked-phase compositing. Per 8-gaussian chunk:
//   A: all 8 weights w[j] (exp2's independent, pipeline)
//   B: short prefix chains (omp product, pa running sum, t1[j])
//   C: 8 independent rcp's (latency amortized)
//   D: 3 parallel per-channel num fma chains
// Long-latency ops (loads, exp, rcp) never sit on a carried chain.
__global__ __launch_bounds__(256, 2) void splat_fwd(
    const float* __restrict__ pos,     // [N,2]
    const float4* __restrict__ P0,
    const float4* __restrict__ P1,
    const float*  __restrict__ P2,
    float* __restrict__ out,           // [N,4]
    int nPairs)
{
    const int t = blockIdx.x * blockDim.x + threadIdx.x;   // pixel-pair index
    if (t >= nPairs) return;

    const float4 pp = reinterpret_cast<const float4*>(pos)[t]; // x0,y0,x1,y1
    const f32x2 px = { pp.x, pp.z };
    const f32x2 py = { pp.y, pp.w };

    f32x2 omp   = { 1.0f, 1.0f };   // running transmittance ~ (1 - pa)
    f32x2 pa    = { 0.0f, 0.0f };   // running sum of t1 (== na, unclipped)
    f32x2 hprev = { 0.0f, 0.0f };   // pa_{k-1} * r_{k-1}; unused at k=0 (num=0)
    f32x2 rlast = { 0.0f, 0.0f };
    f32x2 numr  = { 0.0f, 0.0f };
    f32x2 numg  = { 0.0f, 0.0f };
    f32x2 numb  = { 0.0f, 0.0f };

    for (int c = 0; c < NCHUNK; ++c) {
        const int base = c * CH;

        // batched param fetch for the chunk (uniform -> scalarizes; one wait)
        float4 q0[CH], q1[CH];
        float  q2[CH];
#pragma unroll
        for (int j = 0; j < CH; ++j) {
            q0[j] = P0[base + j];
            q1[j] = P1[base + j];
            q2[j] = P2[base + j];
        }

        // A: weights (fully independent across j)
        f32x2 w[CH];
#pragma unroll
        for (int j = 0; j < CH; ++j) {
            const f32x2 dx = px - q0[j].x;
            const f32x2 dy = py - q0[j].y;
            const f32x2 u  = q0[j].z * dx + q0[j].w * dy;
            const f32x2 e  = dx * u + (q1[j].x * dy) * dy;
            f32x2 E;
            E.x = __builtin_amdgcn_exp2f(e.x);
            E.y = __builtin_amdgcn_exp2f(e.y);
            w[j] = q1[j].y * E;
        }

        // B: prefix chains (each 1 op/iter on its own chain)
        f32x2 t1[CH], paA[CH];
#pragma unroll
        for (int j = 0; j < CH; ++j) {
            t1[j] = w[j] * omp;             // branches off omp chain
            omp   = omp - w[j] * omp;       // omp *= (1 - w[j])  (fma)
            pa    = pa + t1[j];             // running na
            paA[j] = pa;
        }

        // C: reciprocals, all independent
        f32x2 r[CH];
#pragma unroll
        for (int j = 0; j < CH; ++j) {
            const f32x2 nae = paA[j] + 1e-8f;
            r[j].x = __builtin_amdgcn_rcpf(nae.x);
            r[j].y = __builtin_amdgcn_rcpf(nae.y);
        }

        // D: per-channel numerator chains (3 parallel fma chains)
#pragma unroll
        for (int j = 0; j < CH; ++j) {
            numr = numr * hprev + q1[j].z * t1[j];
            numg = numg * hprev + q1[j].w * t1[j];
            numb = numb * hprev + q2[j]   * t1[j];
            hprev = paA[j] * r[j];
        }
        rlast = r[CH - 1];
    }

    const f32x2 pcr = numr * rlast;
    const f32x2 pcg = numg * rlast;
    const f32x2 pcb = numb * rlast;

    float4 o0, o1;
    o0.x = fminf(fmaxf(pcr.x, 0.0f), 255.0f);
    o0.y = fminf(fmaxf(pcg.x, 0.0f), 255.0f);
    o0.z = fminf(fmaxf(pcb.x, 0.0f), 255.0f);
    o0.w = fminf(pa.x, 1.0f) * 255.0f;
    o1.x = fminf(fmaxf(pcr.y, 0.0f), 255.0f);
    o1.y = fminf(fmaxf(pcg.y, 0.0f), 255.0f);
    o1.z = fminf(fmaxf(pcb.y, 0.0f), 255.0f);
    o1.w = fminf(pa.y, 1.0f) * 255.0f;

    float4* o = reinterpret_cast<float4*>(out);
    o[2 * t]     = o0;
    o[2 * t + 1] = o1;
}

extern "C" void kernel_launch(void* const* d_in, const int* in_sizes, int n_in,
                              void* d_out, int out_size, void* d_ws, size_t ws_size,
                              hipStream_t stream) {
    const float* pos    = (const float*)d_in[0];
    const float* mu     = (const float*)d_in[1];
    const float* alpha  = (const float*)d_in[2];
    const float* color  = (const float*)d_in[3];
    const float* scales = (const float*)d_in[4];
    const float* thetas = (const float*)d_in[5];
    float* out = (float*)d_out;

    // Param buffer layout in d_ws: P0[K] | P1[K] | P2[K]
    float4* P0 = (float4*)d_ws;
    float4* P1 = P0 + KG;
    float*  P2 = (float*)(P1 + KG);

    const int n = in_sizes[0] / 2;       // N pixels
    const int nPairs = n / 2;            // N even (512*512)
    const int block = 256;
    const int grid = (nPairs + block - 1) / block;

    hipLaunchKernelGGL(precompute_params, dim3(1), dim3(128), 0, stream,
                       mu, alpha, color, scales, thetas, P0, P1, P2);
    hipLaunchKernelGGL(splat_fwd, dim3(grid), dim3(block), 0, stream,
                       pos, P0, P1, P2, out, nPairs);
}